// Round 1
// baseline (1169.320 us; speedup 1.0000x reference)
//
#include <hip/hip_runtime.h>

// MobileMQA: B=8, C=256, H=W=64, NUM_HEADS=4, hd=64, ds=2
// Pipeline: stats -> pool+norm -> Q gemm (norm fused) -> K/V gemm -> attention -> WO gemm + residual

#define NB 8
#define NC 256
#define NHEADS 4
#define HDIM 64
#define NSP 4096      // H*W
#define MSP 1024      // pooled spatial
#define CNT_INV (1.0f/1048576.0f)
#define EPSV 1e-5f
#define ATT_SCALE 0.125f

// workspace layout (float offsets)
#define WS_STATS 0
#define WS_XDS   64
#define WS_K     (WS_XDS + NB*NC*MSP)        // 64 + 2,097,152
#define WS_V     (WS_K + NB*MSP*HDIM)        // + 524,288
#define WS_Q     (WS_V + NB*MSP*HDIM)        // + 524,288
#define WS_AO    (WS_Q + NB*NC*NSP)          // + 8,388,608
// total = 19,923,008 floats = ~76 MB

// ---------------- stats: per-batch sum / sumsq over C*H*W ----------------
__global__ __launch_bounds__(256) void k_stats(const float* __restrict__ x,
                                               float* __restrict__ stats) {
  const int b = blockIdx.x >> 6;
  const int chunk = blockIdx.x & 63;
  const int t = threadIdx.x;
  const float4* xb = (const float4*)(x + (size_t)b * 1048576 + (size_t)chunk * 16384);
  float s = 0.f, s2 = 0.f;
#pragma unroll
  for (int it = 0; it < 16; ++it) {
    float4 v = xb[it * 256 + t];
    s  += v.x + v.y + v.z + v.w;
    s2 += v.x * v.x + v.y * v.y + v.z * v.z + v.w * v.w;
  }
#pragma unroll
  for (int o = 32; o > 0; o >>= 1) {
    s  += __shfl_down(s, o);
    s2 += __shfl_down(s2, o);
  }
  __shared__ float red[8];
  const int wid = t >> 6;
  if ((t & 63) == 0) { red[wid] = s; red[4 + wid] = s2; }
  __syncthreads();
  if (t == 0) {
    atomicAdd(&stats[b * 2 + 0], red[0] + red[1] + red[2] + red[3]);
    atomicAdd(&stats[b * 2 + 1], red[4] + red[5] + red[6] + red[7]);
  }
}

// ---------------- pool 2x2 + normalize + affine -> xds [b][c][m] ----------------
__global__ __launch_bounds__(256) void k_pool(const float* __restrict__ x,
                                              const float* __restrict__ gnw,
                                              const float* __restrict__ gnb,
                                              const float* __restrict__ stats,
                                              float* __restrict__ xds) {
  const int idx = blockIdx.x * 256 + threadIdx.x;  // over NB*NC*MSP = 2,097,152
  const int wd = idx & 31;
  const int hd = (idx >> 5) & 31;
  const int c  = (idx >> 10) & 255;
  const int b  = idx >> 18;
  const float mu  = stats[b * 2 + 0] * CNT_INV;
  const float ex2 = stats[b * 2 + 1] * CNT_INV;
  const float rstd = rsqrtf(ex2 - mu * mu + EPSV);
  const float* xb = x + (size_t)(b * 256 + c) * 4096 + (hd * 2) * 64 + wd * 2;
  float2 a  = *(const float2*)xb;
  float2 bb = *(const float2*)(xb + 64);
  float avg = (a.x + a.y + bb.x + bb.y) * 0.25f;
  xds[idx] = (avg - mu) * rstd * gnw[c] + gnb[c];
}

// ---------------- Q gemm: q[b,o,n] = sum_c wq[o,c]*xn[b,c,n]; out qT[b][h][n][d] ----------------
__global__ __launch_bounds__(256) void k_gemm_q(const float* __restrict__ wq,
                                                const float* __restrict__ x,
                                                const float* __restrict__ stats,
                                                const float* __restrict__ gnw,
                                                const float* __restrict__ gnb,
                                                float* __restrict__ qout) {
  __shared__ float As[16][68];
  __shared__ float Bs[16][68];
  __shared__ float Cs[64][68];
  const int t = threadIdx.x;
  const int tx = t & 15, ty = t >> 4;
  const int n0 = blockIdx.x * 64;
  const int h = blockIdx.y;
  const int b = blockIdx.z;
  const int m0 = h * 64;
  const float mu = stats[b * 2 + 0] * CNT_INV;
  const float rstd = rsqrtf(stats[b * 2 + 1] * CNT_INV - mu * mu + EPSV);
  float acc[4][4] = {};
  const int amr = t >> 2, akc = (t & 3) * 4;   // A loader
  const int bkr = t >> 4, bnc = (t & 15) * 4;  // B loader
  for (int kk = 0; kk < 256; kk += 16) {
    float4 a4 = *(const float4*)&wq[(m0 + amr) * 256 + kk + akc];
    const int c = kk + bkr;
    float4 b4 = *(const float4*)&x[(size_t)(b * 256 + c) * 4096 + n0 + bnc];
    const float gw = gnw[c] * rstd;
    const float gb = gnb[c] - mu * rstd * gnw[c];
    b4.x = b4.x * gw + gb; b4.y = b4.y * gw + gb;
    b4.z = b4.z * gw + gb; b4.w = b4.w * gw + gb;
    __syncthreads();
    As[akc + 0][amr] = a4.x; As[akc + 1][amr] = a4.y;
    As[akc + 2][amr] = a4.z; As[akc + 3][amr] = a4.w;
    *(float4*)&Bs[bkr][bnc] = b4;
    __syncthreads();
#pragma unroll
    for (int k = 0; k < 16; ++k) {
      float4 av = *(const float4*)&As[k][ty * 4];
      float4 bv = *(const float4*)&Bs[k][tx * 4];
      const float a_[4] = {av.x, av.y, av.z, av.w};
      const float b_[4] = {bv.x, bv.y, bv.z, bv.w};
#pragma unroll
      for (int i = 0; i < 4; ++i)
#pragma unroll
        for (int j = 0; j < 4; ++j) acc[i][j] += a_[i] * b_[j];
    }
  }
  __syncthreads();
#pragma unroll
  for (int i = 0; i < 4; ++i)
#pragma unroll
    for (int j = 0; j < 4; ++j) Cs[tx * 4 + j][ty * 4 + i] = acc[i][j];
  __syncthreads();
  {
    const int n = t >> 2, d4 = (t & 3) * 16;
    float* dst = qout + ((size_t)(b * 4 + h) * 4096 + n0 + n) * 64 + d4;
#pragma unroll
    for (int u = 0; u < 4; ++u)
      *(float4*)(dst + u * 4) = *(const float4*)&Cs[n][d4 + u * 4];
  }
}

// ---------------- K/V gemm: out kT/vT [b][m][d] ----------------
__global__ __launch_bounds__(256) void k_gemm_kv(const float* __restrict__ wk,
                                                 const float* __restrict__ wv,
                                                 const float* __restrict__ xds,
                                                 float* __restrict__ outk,
                                                 float* __restrict__ outv) {
  __shared__ float As[16][68];
  __shared__ float Bs[16][68];
  __shared__ float Cs[64][68];
  const int t = threadIdx.x;
  const int tx = t & 15, ty = t >> 4;
  const int n0 = blockIdx.x * 64;
  const float* A = (blockIdx.y == 0) ? wk : wv;
  float* outp = (blockIdx.y == 0) ? outk : outv;
  const int b = blockIdx.z;
  float acc[4][4] = {};
  const int amr = t >> 2, akc = (t & 3) * 4;
  const int bkr = t >> 4, bnc = (t & 15) * 4;
  for (int kk = 0; kk < 256; kk += 16) {
    float4 a4 = *(const float4*)&A[amr * 256 + kk + akc];
    const int c = kk + bkr;
    float4 b4 = *(const float4*)&xds[(size_t)(b * 256 + c) * 1024 + n0 + bnc];
    __syncthreads();
    As[akc + 0][amr] = a4.x; As[akc + 1][amr] = a4.y;
    As[akc + 2][amr] = a4.z; As[akc + 3][amr] = a4.w;
    *(float4*)&Bs[bkr][bnc] = b4;
    __syncthreads();
#pragma unroll
    for (int k = 0; k < 16; ++k) {
      float4 av = *(const float4*)&As[k][ty * 4];
      float4 bv = *(const float4*)&Bs[k][tx * 4];
      const float a_[4] = {av.x, av.y, av.z, av.w};
      const float b_[4] = {bv.x, bv.y, bv.z, bv.w};
#pragma unroll
      for (int i = 0; i < 4; ++i)
#pragma unroll
        for (int j = 0; j < 4; ++j) acc[i][j] += a_[i] * b_[j];
    }
  }
  __syncthreads();
#pragma unroll
  for (int i = 0; i < 4; ++i)
#pragma unroll
    for (int j = 0; j < 4; ++j) Cs[tx * 4 + j][ty * 4 + i] = acc[i][j];
  __syncthreads();
  {
    const int n = t >> 2, d4 = (t & 3) * 16;
    float* dst = outp + (size_t)b * 65536 + (size_t)(n0 + n) * 64 + d4;
#pragma unroll
    for (int u = 0; u < 4; ++u)
      *(float4*)(dst + u * 4) = *(const float4*)&Cs[n][d4 + u * 4];
  }
}

// ---------------- attention: per (b,h,64-row q tile), streaming softmax (no max) ----------------
__global__ __launch_bounds__(256) void k_attn(const float* __restrict__ qT,
                                              const float* __restrict__ kT,
                                              const float* __restrict__ vT,
                                              float* __restrict__ ao) {
  __shared__ float qs[64][68];
  __shared__ float kv[64][68];
  __shared__ float ps[64][68];
  __shared__ float den[64];
  const int t = threadIdx.x;
  const int nt = blockIdx.x, h = blockIdx.y, b = blockIdx.z;
  const float* qbase = qT + ((size_t)(b * 4 + h) * 4096 + nt * 64) * 64;
  {
    const int r = t >> 2, c4 = (t & 3) * 16;
    const float* src = qbase + r * 64 + c4;
#pragma unroll
    for (int u = 0; u < 4; ++u)
      *(float4*)&qs[r][c4 + u * 4] = *(const float4*)(src + u * 4);
  }
  if (t < 64) den[t] = 0.f;
  float oacc[4][4] = {};                 // [i][dd]; r=tr+i*16, d=td*4+dd
  const int tj = t & 15, tr = t >> 4;
  const int td = tj;
  const float* kb = kT + (size_t)b * 65536;
  const float* vb = vT + (size_t)b * 65536;
  __syncthreads();
  for (int mt = 0; mt < 16; ++mt) {
    {  // load K tile (prev-iter readers finished at loop-end barrier)
      const int r = t >> 2, c4 = (t & 3) * 16;
      const float* src = kb + (size_t)(mt * 64 + r) * 64 + c4;
#pragma unroll
      for (int u = 0; u < 4; ++u)
        *(float4*)&kv[r][c4 + u * 4] = *(const float4*)(src + u * 4);
    }
    __syncthreads();
    float sacc[4][4] = {};
#pragma unroll
    for (int d4 = 0; d4 < 64; d4 += 4) {
      float4 qv[4], kvv[4];
#pragma unroll
      for (int i = 0; i < 4; ++i) qv[i] = *(const float4*)&qs[tr + i * 16][d4];
#pragma unroll
      for (int j = 0; j < 4; ++j) kvv[j] = *(const float4*)&kv[tj + j * 16][d4];
#pragma unroll
      for (int i = 0; i < 4; ++i)
#pragma unroll
        for (int j = 0; j < 4; ++j)
          sacc[i][j] += qv[i].x * kvv[j].x + qv[i].y * kvv[j].y +
                        qv[i].z * kvv[j].z + qv[i].w * kvv[j].w;
    }
#pragma unroll
    for (int i = 0; i < 4; ++i)
#pragma unroll
      for (int j = 0; j < 4; ++j)
        ps[tr + i * 16][tj + j * 16] = __expf(sacc[i][j] * ATT_SCALE);
    __syncthreads();
    if (t < 64) {
      float s = 0.f;
#pragma unroll
      for (int j = 0; j < 64; ++j) s += ps[t][j];
      den[t] += s;
    }
    {  // load V tile into kv (K readers finished at barrier above)
      const int r = t >> 2, c4 = (t & 3) * 16;
      const float* src = vb + (size_t)(mt * 64 + r) * 64 + c4;
#pragma unroll
      for (int u = 0; u < 4; ++u)
        *(float4*)&kv[r][c4 + u * 4] = *(const float4*)(src + u * 4);
    }
    __syncthreads();
    // PV accumulate
#pragma unroll
    for (int j0 = 0; j0 < 64; j0 += 4) {
      float4 pv[4], vv[4];
#pragma unroll
      for (int i = 0; i < 4; ++i) pv[i] = *(const float4*)&ps[tr + i * 16][j0];
#pragma unroll
      for (int jj = 0; jj < 4; ++jj) vv[jj] = *(const float4*)&kv[j0 + jj][td * 4];
#pragma unroll
      for (int i = 0; i < 4; ++i) {
        oacc[i][0] += pv[i].x * vv[0].x + pv[i].y * vv[1].x + pv[i].z * vv[2].x + pv[i].w * vv[3].x;
        oacc[i][1] += pv[i].x * vv[0].y + pv[i].y * vv[1].y + pv[i].z * vv[2].y + pv[i].w * vv[3].y;
        oacc[i][2] += pv[i].x * vv[0].z + pv[i].y * vv[1].z + pv[i].z * vv[2].z + pv[i].w * vv[3].z;
        oacc[i][3] += pv[i].x * vv[0].w + pv[i].y * vv[1].w + pv[i].z * vv[2].w + pv[i].w * vv[3].w;
      }
    }
    __syncthreads();
  }
  float invd[4];
#pragma unroll
  for (int i = 0; i < 4; ++i) invd[i] = 1.f / den[tr + i * 16];
  // stage transposed [d][r] into qs for coalesced output
#pragma unroll
  for (int i = 0; i < 4; ++i)
#pragma unroll
    for (int dd = 0; dd < 4; ++dd)
      qs[td * 4 + dd][tr + i * 16] = oacc[i][dd] * invd[i];
  __syncthreads();
  {
    const int d = t >> 2, r4 = (t & 3) * 16;
    float* dst = ao + ((size_t)(b * 256 + h * 64 + d)) * 4096 + nt * 64 + r4;
#pragma unroll
    for (int u = 0; u < 4; ++u)
      *(float4*)(dst + u * 4) = *(const float4*)&qs[d][r4 + u * 4];
  }
}

// ---------------- WO gemm + residual: out = x + gamma[o]*(wo@ao) ----------------
__global__ __launch_bounds__(256) void k_gemm_wo(const float* __restrict__ wo,
                                                 const float* __restrict__ ao,
                                                 const float* __restrict__ x,
                                                 const float* __restrict__ gamma,
                                                 float* __restrict__ outp) {
  __shared__ float As[16][68];
  __shared__ float Bs[16][68];
  const int t = threadIdx.x;
  const int tx = t & 15, ty = t >> 4;
  const int n0 = blockIdx.x * 64;
  const int m0 = blockIdx.y * 64;
  const int b = blockIdx.z;
  float acc[4][4] = {};
  const int amr = t >> 2, akc = (t & 3) * 4;
  const int bkr = t >> 4, bnc = (t & 15) * 4;
  for (int kk = 0; kk < 256; kk += 16) {
    float4 a4 = *(const float4*)&wo[(m0 + amr) * 256 + kk + akc];
    const int c = kk + bkr;
    float4 b4 = *(const float4*)&ao[(size_t)(b * 256 + c) * 4096 + n0 + bnc];
    __syncthreads();
    As[akc + 0][amr] = a4.x; As[akc + 1][amr] = a4.y;
    As[akc + 2][amr] = a4.z; As[akc + 3][amr] = a4.w;
    *(float4*)&Bs[bkr][bnc] = b4;
    __syncthreads();
#pragma unroll
    for (int k = 0; k < 16; ++k) {
      float4 av = *(const float4*)&As[k][ty * 4];
      float4 bv = *(const float4*)&Bs[k][tx * 4];
      const float a_[4] = {av.x, av.y, av.z, av.w};
      const float b_[4] = {bv.x, bv.y, bv.z, bv.w};
#pragma unroll
      for (int i = 0; i < 4; ++i)
#pragma unroll
        for (int j = 0; j < 4; ++j) acc[i][j] += a_[i] * b_[j];
    }
  }
#pragma unroll
  for (int i = 0; i < 4; ++i) {
    const int o = m0 + ty * 4 + i;
    const float g = gamma[o];
    const size_t idx = (size_t)(b * 256 + o) * 4096 + n0 + tx * 4;
    float4 xr = *(const float4*)&x[idx];
    float4 r;
    r.x = xr.x + g * acc[i][0];
    r.y = xr.y + g * acc[i][1];
    r.z = xr.z + g * acc[i][2];
    r.w = xr.w + g * acc[i][3];
    *(float4*)&outp[idx] = r;
  }
}

extern "C" void kernel_launch(void* const* d_in, const int* in_sizes, int n_in,
                              void* d_out, int out_size, void* d_ws, size_t ws_size,
                              hipStream_t stream) {
  const float* x     = (const float*)d_in[0];
  const float* gnw   = (const float*)d_in[1];
  const float* gnb   = (const float*)d_in[2];
  const float* wq    = (const float*)d_in[3];
  const float* wk    = (const float*)d_in[4];
  const float* wv    = (const float*)d_in[5];
  const float* wo    = (const float*)d_in[6];
  const float* gamma = (const float*)d_in[7];
  float* out = (float*)d_out;
  float* ws  = (float*)d_ws;

  hipMemsetAsync(ws, 0, 256, stream);
  k_stats<<<512, 256, 0, stream>>>(x, ws + WS_STATS);
  k_pool<<<8192, 256, 0, stream>>>(x, gnw, gnb, ws + WS_STATS, ws + WS_XDS);
  k_gemm_q<<<dim3(64, 4, 8), 256, 0, stream>>>(wq, x, ws + WS_STATS, gnw, gnb, ws + WS_Q);
  k_gemm_kv<<<dim3(16, 2, 8), 256, 0, stream>>>(wk, wv, ws + WS_XDS, ws + WS_K, ws + WS_V);
  k_attn<<<dim3(64, 4, 8), 256, 0, stream>>>(ws + WS_Q, ws + WS_K, ws + WS_V, ws + WS_AO);
  k_gemm_wo<<<dim3(64, 4, 8), 256, 0, stream>>>(wo, ws + WS_AO, x, gamma, out);
}

// Round 2
// 366.484 us; speedup vs baseline: 3.1906x; 3.1906x over previous
//
#include <hip/hip_runtime.h>

// MobileMQA: B=8, C=256, H=W=64, NUM_HEADS=4, hd=64, ds=2
// Pipeline: stats -> pool+norm -> Q gemm (norm fused, bf16 out) -> K/V gemm (bf16 out)
//           -> MFMA attention (bf16, barrier-free) -> WO gemm + residual (fp32)

#define CNT_INV (1.0f/1048576.0f)
#define EPSV 1e-5f
#define ATT_SCALE 0.125f

// workspace layout (float offsets)
#define WS_STATS 0
#define WS_XDS   64                       // fp32 [b][c][m]   2,097,152
#define WS_AO    (WS_XDS + 8*256*1024)    // fp32 [b][c][n]   8,388,608
#define WS_QBF   (WS_AO + 8*256*4096)     // bf16 [b][h][n][d] 8,388,608 bf16 = 4,194,304 f
#define WS_KBF   (WS_QBF + 8*4*4096*32)   // bf16 [b][m][d]    524,288 bf16 = 262,144 f
#define WS_VBF   (WS_KBF + 8*1024*32)     // bf16 [b][d][m]    524,288 bf16 = 262,144 f
// total = 15,204,416 floats ~ 61 MB

typedef __attribute__((ext_vector_type(8))) short bf8_t;   // 8 bf16 (4 VGPRs) MFMA A/B frag
typedef __attribute__((ext_vector_type(4))) short s4_t;    // 4 bf16 (8B)
typedef __attribute__((ext_vector_type(4))) float f4_t;    // MFMA C/D frag

static __device__ __forceinline__ unsigned short f2bf(float f) {
  union { float f; unsigned u; } v; v.f = f;
  unsigned r = v.u + 0x7fffu + ((v.u >> 16) & 1u);  // RNE
  return (unsigned short)(r >> 16);
}

// ---------------- stats: per-batch sum / sumsq over C*H*W ----------------
__global__ __launch_bounds__(256) void k_stats(const float* __restrict__ x,
                                               float* __restrict__ stats) {
  const int b = blockIdx.x >> 6;
  const int chunk = blockIdx.x & 63;
  const int t = threadIdx.x;
  const float4* xb = (const float4*)(x + (size_t)b * 1048576 + (size_t)chunk * 16384);
  float s = 0.f, s2 = 0.f;
#pragma unroll
  for (int it = 0; it < 16; ++it) {
    float4 v = xb[it * 256 + t];
    s  += v.x + v.y + v.z + v.w;
    s2 += v.x * v.x + v.y * v.y + v.z * v.z + v.w * v.w;
  }
#pragma unroll
  for (int o = 32; o > 0; o >>= 1) {
    s  += __shfl_down(s, o);
    s2 += __shfl_down(s2, o);
  }
  __shared__ float red[8];
  const int wid = t >> 6;
  if ((t & 63) == 0) { red[wid] = s; red[4 + wid] = s2; }
  __syncthreads();
  if (t == 0) {
    atomicAdd(&stats[b * 2 + 0], red[0] + red[1] + red[2] + red[3]);
    atomicAdd(&stats[b * 2 + 1], red[4] + red[5] + red[6] + red[7]);
  }
}

// ---------------- pool 2x2 + normalize + affine -> xds [b][c][m] ----------------
__global__ __launch_bounds__(256) void k_pool(const float* __restrict__ x,
                                              const float* __restrict__ gnw,
                                              const float* __restrict__ gnb,
                                              const float* __restrict__ stats,
                                              float* __restrict__ xds) {
  const int idx = blockIdx.x * 256 + threadIdx.x;
  const int wd = idx & 31;
  const int hd = (idx >> 5) & 31;
  const int c  = (idx >> 10) & 255;
  const int b  = idx >> 18;
  const float mu  = stats[b * 2 + 0] * CNT_INV;
  const float ex2 = stats[b * 2 + 1] * CNT_INV;
  const float rstd = rsqrtf(ex2 - mu * mu + EPSV);
  const float* xb = x + (size_t)(b * 256 + c) * 4096 + (hd * 2) * 64 + wd * 2;
  float2 a  = *(const float2*)xb;
  float2 bb = *(const float2*)(xb + 64);
  float avg = (a.x + a.y + bb.x + bb.y) * 0.25f;
  xds[idx] = (avg - mu) * rstd * gnw[c] + gnb[c];
}

// ---------------- Q gemm: qbf[b][h][n][d] bf16 ----------------
__global__ __launch_bounds__(256) void k_gemm_q(const float* __restrict__ wq,
                                                const float* __restrict__ x,
                                                const float* __restrict__ stats,
                                                const float* __restrict__ gnw,
                                                const float* __restrict__ gnb,
                                                unsigned short* __restrict__ qout) {
  __shared__ float As[16][68];
  __shared__ float Bs[16][68];
  __shared__ float Cs[64][68];
  const int t = threadIdx.x;
  const int tx = t & 15, ty = t >> 4;
  const int n0 = blockIdx.x * 64;
  const int h = blockIdx.y;
  const int b = blockIdx.z;
  const int m0 = h * 64;
  const float mu = stats[b * 2 + 0] * CNT_INV;
  const float rstd = rsqrtf(stats[b * 2 + 1] * CNT_INV - mu * mu + EPSV);
  float acc[4][4] = {};
  const int amr = t >> 2, akc = (t & 3) * 4;
  const int bkr = t >> 4, bnc = (t & 15) * 4;
  for (int kk = 0; kk < 256; kk += 16) {
    float4 a4 = *(const float4*)&wq[(m0 + amr) * 256 + kk + akc];
    const int c = kk + bkr;
    float4 b4 = *(const float4*)&x[(size_t)(b * 256 + c) * 4096 + n0 + bnc];
    const float gw = gnw[c] * rstd;
    const float gb = gnb[c] - mu * rstd * gnw[c];
    b4.x = b4.x * gw + gb; b4.y = b4.y * gw + gb;
    b4.z = b4.z * gw + gb; b4.w = b4.w * gw + gb;
    __syncthreads();
    As[akc + 0][amr] = a4.x; As[akc + 1][amr] = a4.y;
    As[akc + 2][amr] = a4.z; As[akc + 3][amr] = a4.w;
    *(float4*)&Bs[bkr][bnc] = b4;
    __syncthreads();
#pragma unroll
    for (int k = 0; k < 16; ++k) {
      float4 av = *(const float4*)&As[k][ty * 4];
      float4 bv = *(const float4*)&Bs[k][tx * 4];
      const float a_[4] = {av.x, av.y, av.z, av.w};
      const float b_[4] = {bv.x, bv.y, bv.z, bv.w};
#pragma unroll
      for (int i = 0; i < 4; ++i)
#pragma unroll
        for (int j = 0; j < 4; ++j) acc[i][j] += a_[i] * b_[j];
    }
  }
  __syncthreads();
#pragma unroll
  for (int i = 0; i < 4; ++i)
#pragma unroll
    for (int j = 0; j < 4; ++j) Cs[tx * 4 + j][ty * 4 + i] = acc[i][j];
  __syncthreads();
  {
    const int n = t >> 2, d4 = (t & 3) * 16;
    unsigned short* dst = qout + ((size_t)(b * 4 + h) * 4096 + n0 + n) * 64 + d4;
#pragma unroll
    for (int u = 0; u < 4; ++u) {
      float4 v = *(const float4*)&Cs[n][d4 + u * 4];
      s4_t p; p[0] = (short)f2bf(v.x); p[1] = (short)f2bf(v.y);
      p[2] = (short)f2bf(v.z); p[3] = (short)f2bf(v.w);
      *(s4_t*)(dst + u * 4) = p;
    }
  }
}

// ---------------- K/V gemm: kbf [b][m][d] bf16, vtbf [b][d][m] bf16 ----------------
__global__ __launch_bounds__(256) void k_gemm_kv(const float* __restrict__ wk,
                                                 const float* __restrict__ wv,
                                                 const float* __restrict__ xds,
                                                 unsigned short* __restrict__ outk,
                                                 unsigned short* __restrict__ outv) {
  __shared__ float As[16][68];
  __shared__ float Bs[16][68];
  __shared__ float Cs[64][68];
  const int t = threadIdx.x;
  const int tx = t & 15, ty = t >> 4;
  const int n0 = blockIdx.x * 64;
  const int isK = (blockIdx.y == 0);
  const float* A = isK ? wk : wv;
  const int b = blockIdx.z;
  float acc[4][4] = {};
  const int amr = t >> 2, akc = (t & 3) * 4;
  const int bkr = t >> 4, bnc = (t & 15) * 4;
  for (int kk = 0; kk < 256; kk += 16) {
    float4 a4 = *(const float4*)&A[amr * 256 + kk + akc];
    const int c = kk + bkr;
    float4 b4 = *(const float4*)&xds[(size_t)(b * 256 + c) * 1024 + n0 + bnc];
    __syncthreads();
    As[akc + 0][amr] = a4.x; As[akc + 1][amr] = a4.y;
    As[akc + 2][amr] = a4.z; As[akc + 3][amr] = a4.w;
    *(float4*)&Bs[bkr][bnc] = b4;
    __syncthreads();
#pragma unroll
    for (int k = 0; k < 16; ++k) {
      float4 av = *(const float4*)&As[k][ty * 4];
      float4 bv = *(const float4*)&Bs[k][tx * 4];
      const float a_[4] = {av.x, av.y, av.z, av.w};
      const float b_[4] = {bv.x, bv.y, bv.z, bv.w};
#pragma unroll
      for (int i = 0; i < 4; ++i)
#pragma unroll
        for (int j = 0; j < 4; ++j) acc[i][j] += a_[i] * b_[j];
    }
  }
  if (isK) {  // transpose to [m][d] via Cs, then bf16 store
    __syncthreads();
#pragma unroll
    for (int i = 0; i < 4; ++i)
#pragma unroll
      for (int j = 0; j < 4; ++j) Cs[tx * 4 + j][ty * 4 + i] = acc[i][j];
    __syncthreads();
    const int n = t >> 2, d4 = (t & 3) * 16;
    unsigned short* dst = outk + (size_t)b * 65536 + (size_t)(n0 + n) * 64 + d4;
#pragma unroll
    for (int u = 0; u < 4; ++u) {
      float4 v = *(const float4*)&Cs[n][d4 + u * 4];
      s4_t p; p[0] = (short)f2bf(v.x); p[1] = (short)f2bf(v.y);
      p[2] = (short)f2bf(v.z); p[3] = (short)f2bf(v.w);
      *(s4_t*)(dst + u * 4) = p;
    }
  } else {  // V natural layout [d][m], direct bf16 store
#pragma unroll
    for (int i = 0; i < 4; ++i) {
      const int d = ty * 4 + i;
      s4_t p; p[0] = (short)f2bf(acc[i][0]); p[1] = (short)f2bf(acc[i][1]);
      p[2] = (short)f2bf(acc[i][2]); p[3] = (short)f2bf(acc[i][3]);
      *(s4_t*)(outv + (size_t)b * 65536 + (size_t)d * 1024 + n0 + tx * 4) = p;
    }
  }
}

// ---------------- MFMA attention: barrier-free, per-wave 32 q rows ----------------
// S^T = K·Q^T  (A=K[kv][d], B=Q^T -> C rows=kv, cols=q)
// O^T = V^T·P^T (A=V^T[d][kv], B=P^T via LDS -> C rows=d, cols=q) -> direct [c][n] store
__global__ __launch_bounds__(256) void k_attn_mfma(const unsigned short* __restrict__ qbf,
                                                   const unsigned short* __restrict__ kbf,
                                                   const unsigned short* __restrict__ vtbf,
                                                   float* __restrict__ ao) {
  __shared__ __align__(16) unsigned short plds[4][32][36];  // per-wave P stage [q][kv]
  const int t = threadIdx.x;
  const int w = t >> 6;
  const int l = t & 63;
  const int lane16 = l & 15;
  const int quad = l >> 4;
  const int h = blockIdx.y, b = blockIdx.z;
  const int q0 = blockIdx.x * 128 + w * 32;

  const unsigned short* qb = qbf + ((size_t)(b * 4 + h) * 4096 + q0) * 64;
  const unsigned short* kb = kbf + (size_t)b * 65536;
  const unsigned short* vb = vtbf + (size_t)b * 65536;

  bf8_t Qf[2][2];
#pragma unroll
  for (int qg = 0; qg < 2; ++qg)
#pragma unroll
    for (int dc = 0; dc < 2; ++dc)
      Qf[qg][dc] = *(const bf8_t*)(qb + (qg * 16 + lane16) * 64 + dc * 32 + quad * 8);

  f4_t O[4][2];
#pragma unroll
  for (int dg = 0; dg < 4; ++dg)
#pragma unroll
    for (int qg = 0; qg < 2; ++qg) O[dg][qg] = (f4_t){0.f, 0.f, 0.f, 0.f};
  float den[2] = {0.f, 0.f};

  for (int kv0 = 0; kv0 < 1024; kv0 += 32) {
    bf8_t Kf[2][2];
#pragma unroll
    for (int s = 0; s < 2; ++s)
#pragma unroll
      for (int dc = 0; dc < 2; ++dc)
        Kf[s][dc] = *(const bf8_t*)(kb + (size_t)(kv0 + s * 16 + lane16) * 64 + dc * 32 + quad * 8);
    bf8_t Vf[4];
#pragma unroll
    for (int dg = 0; dg < 4; ++dg)
      Vf[dg] = *(const bf8_t*)(vb + (size_t)(dg * 16 + lane16) * 1024 + kv0 + quad * 8);

#pragma unroll
    for (int qg = 0; qg < 2; ++qg)
#pragma unroll
      for (int s = 0; s < 2; ++s) {
        f4_t S = (f4_t){0.f, 0.f, 0.f, 0.f};
        S = __builtin_amdgcn_mfma_f32_16x16x32_bf16(Kf[s][0], Qf[qg][0], S, 0, 0, 0);
        S = __builtin_amdgcn_mfma_f32_16x16x32_bf16(Kf[s][1], Qf[qg][1], S, 0, 0, 0);
        float e0 = __expf(S[0] * ATT_SCALE);
        float e1 = __expf(S[1] * ATT_SCALE);
        float e2 = __expf(S[2] * ATT_SCALE);
        float e3 = __expf(S[3] * ATT_SCALE);
        den[qg] += (e0 + e1) + (e2 + e3);
        s4_t p; p[0] = (short)f2bf(e0); p[1] = (short)f2bf(e1);
        p[2] = (short)f2bf(e2); p[3] = (short)f2bf(e3);
        *(s4_t*)&plds[w][qg * 16 + lane16][s * 16 + quad * 4] = p;
      }

    bf8_t Pf[2];
#pragma unroll
    for (int qg = 0; qg < 2; ++qg)
      Pf[qg] = *(const bf8_t*)&plds[w][qg * 16 + lane16][quad * 8];
#pragma unroll
    for (int dg = 0; dg < 4; ++dg)
#pragma unroll
      for (int qg = 0; qg < 2; ++qg)
        O[dg][qg] = __builtin_amdgcn_mfma_f32_16x16x32_bf16(Vf[dg], Pf[qg], O[dg][qg], 0, 0, 0);
  }

  float rden[2];
#pragma unroll
  for (int qg = 0; qg < 2; ++qg) {
    float d = den[qg];
    d += __shfl_xor(d, 16);
    d += __shfl_xor(d, 32);
    rden[qg] = 1.f / d;
  }

#pragma unroll
  for (int dg = 0; dg < 4; ++dg)
#pragma unroll
    for (int qg = 0; qg < 2; ++qg) {
      const int c = h * 64 + dg * 16 + quad * 4;
      float* dst = ao + ((size_t)(b * 256 + c)) * 4096 + q0 + qg * 16 + lane16;
#pragma unroll
      for (int r = 0; r < 4; ++r)
        dst[(size_t)r * 4096] = O[dg][qg][r] * rden[qg];
    }
}

// ---------------- WO gemm + residual: out = x + gamma[o]*(wo@ao) ----------------
__global__ __launch_bounds__(256) void k_gemm_wo(const float* __restrict__ wo,
                                                 const float* __restrict__ ao,
                                                 const float* __restrict__ x,
                                                 const float* __restrict__ gamma,
                                                 float* __restrict__ outp) {
  __shared__ float As[16][68];
  __shared__ float Bs[16][68];
  const int t = threadIdx.x;
  const int tx = t & 15, ty = t >> 4;
  const int n0 = blockIdx.x * 64;
  const int m0 = blockIdx.y * 64;
  const int b = blockIdx.z;
  float acc[4][4] = {};
  const int amr = t >> 2, akc = (t & 3) * 4;
  const int bkr = t >> 4, bnc = (t & 15) * 4;
  for (int kk = 0; kk < 256; kk += 16) {
    float4 a4 = *(const float4*)&wo[(m0 + amr) * 256 + kk + akc];
    const int c = kk + bkr;
    float4 b4 = *(const float4*)&ao[(size_t)(b * 256 + c) * 4096 + n0 + bnc];
    __syncthreads();
    As[akc + 0][amr] = a4.x; As[akc + 1][amr] = a4.y;
    As[akc + 2][amr] = a4.z; As[akc + 3][amr] = a4.w;
    *(float4*)&Bs[bkr][bnc] = b4;
    __syncthreads();
#pragma unroll
    for (int k = 0; k < 16; ++k) {
      float4 av = *(const float4*)&As[k][ty * 4];
      float4 bv = *(const float4*)&Bs[k][tx * 4];
      const float a_[4] = {av.x, av.y, av.z, av.w};
      const float b_[4] = {bv.x, bv.y, bv.z, bv.w};
#pragma unroll
      for (int i = 0; i < 4; ++i)
#pragma unroll
        for (int j = 0; j < 4; ++j) acc[i][j] += a_[i] * b_[j];
    }
  }
#pragma unroll
  for (int i = 0; i < 4; ++i) {
    const int o = m0 + ty * 4 + i;
    const float g = gamma[o];
    const size_t idx = (size_t)(b * 256 + o) * 4096 + n0 + tx * 4;
    float4 xr = *(const float4*)&x[idx];
    float4 r;
    r.x = xr.x + g * acc[i][0];
    r.y = xr.y + g * acc[i][1];
    r.z = xr.z + g * acc[i][2];
    r.w = xr.w + g * acc[i][3];
    *(float4*)&outp[idx] = r;
  }
}

extern "C" void kernel_launch(void* const* d_in, const int* in_sizes, int n_in,
                              void* d_out, int out_size, void* d_ws, size_t ws_size,
                              hipStream_t stream) {
  const float* x     = (const float*)d_in[0];
  const float* gnw   = (const float*)d_in[1];
  const float* gnb   = (const float*)d_in[2];
  const float* wq    = (const float*)d_in[3];
  const float* wk    = (const float*)d_in[4];
  const float* wv    = (const float*)d_in[5];
  const float* wo    = (const float*)d_in[6];
  const float* gamma = (const float*)d_in[7];
  float* out = (float*)d_out;
  float* ws  = (float*)d_ws;
  unsigned short* qbf  = (unsigned short*)(ws + WS_QBF);
  unsigned short* kbf  = (unsigned short*)(ws + WS_KBF);
  unsigned short* vtbf = (unsigned short*)(ws + WS_VBF);

  hipMemsetAsync(ws, 0, 256, stream);
  k_stats<<<512, 256, 0, stream>>>(x, ws + WS_STATS);
  k_pool<<<8192, 256, 0, stream>>>(x, gnw, gnb, ws + WS_STATS, ws + WS_XDS);
  k_gemm_q<<<dim3(64, 4, 8), 256, 0, stream>>>(wq, x, ws + WS_STATS, gnw, gnb, qbf);
  k_gemm_kv<<<dim3(16, 2, 8), 256, 0, stream>>>(wk, wv, ws + WS_XDS, kbf, vtbf);
  k_attn_mfma<<<dim3(32, 4, 8), 256, 0, stream>>>(qbf, kbf, vtbf, ws + WS_AO);
  k_gemm_wo<<<dim3(64, 4, 8), 256, 0, stream>>>(wo, ws + WS_AO, x, gamma, out);
}

// Round 3
// 258.213 us; speedup vs baseline: 4.5285x; 1.4193x over previous
//
#include <hip/hip_runtime.h>

// MobileMQA: B=8, C=256, H=W=64, NUM_HEADS=4, hd=64, ds=2
// R3: all-MFMA bf16 pipeline, staging-free GEMMs (direct 16B global frag loads),
//     bf16 transposed intermediates, attention with K/V prefetch + perm packing.

#define CNT_INV (1.0f/1048576.0f)
#define EPSV 1e-5f
#define ATT_SCALE 0.125f

// workspace layout (float offsets)
#define WS_STATS 0                    // 64
#define WS_XNT   64                   // bf16 xnT [b][n][c]  8,388,608 u16 = 4,194,304 f
#define WS_XDS   4194368              // bf16 xdsT [b][m][c] 2,097,152 u16 = 1,048,576 f
#define WS_Q     5242944              // bf16 qT  [b][h][n][d] = 4,194,304 f
#define WS_K     9437248              // bf16 k   [b][m][d]  = 262,144 f
#define WS_V     9699392              // bf16 vT  [b][d][m]  = 262,144 f
#define WS_AOT   9961536              // bf16 aoT [b][n][c]  = 4,194,304 f
#define WS_WQB   14155840             // bf16 wq  [o][c]     = 32,768 f
#define WS_WKV   14188608             // bf16 [wk;wv] [128][256] = 16,384 f
#define WS_WOB   14204992             // bf16 wo  [o][c]     = 32,768 f
// total 14,237,760 floats ~ 57 MB

typedef __attribute__((ext_vector_type(8))) short bf8_t;   // 8 bf16 MFMA A/B frag
typedef __attribute__((ext_vector_type(4))) float f4_t;    // MFMA C/D frag

static __device__ __forceinline__ unsigned fbits(float f) {
  union { float f; unsigned u; } v; v.f = f; return v.u;
}
static __device__ __forceinline__ unsigned short f2bf(float f) {  // RNE
  unsigned u = fbits(f);
  return (unsigned short)((u + 0x7fffu + ((u >> 16) & 1u)) >> 16);
}
// pack two floats -> (bf16(b)<<16)|bf16(a), round-half-up, 3 VALU ops
static __device__ __forceinline__ unsigned pk_rnd(float a, float b) {
  return __builtin_amdgcn_perm(fbits(b) + 0x8000u, fbits(a) + 0x8000u, 0x07060302u);
}
// truncating pack, 1 VALU op
static __device__ __forceinline__ unsigned pk_tr(float a, float b) {
  return __builtin_amdgcn_perm(fbits(b), fbits(a), 0x07060302u);
}
static __device__ __forceinline__ float bf2f(unsigned short h) {
  union { unsigned u; float f; } v; v.u = ((unsigned)h) << 16; return v.f;
}

// ---------------- stats: per-batch sum / sumsq ----------------
__global__ __launch_bounds__(256) void k_stats(const float* __restrict__ x,
                                               float* __restrict__ stats) {
  const int b = blockIdx.x >> 6;
  const int chunk = blockIdx.x & 63;
  const int t = threadIdx.x;
  const float4* xb = (const float4*)(x + (size_t)b * 1048576 + (size_t)chunk * 16384);
  float s = 0.f, s2 = 0.f;
#pragma unroll
  for (int it = 0; it < 16; ++it) {
    float4 v = xb[it * 256 + t];
    s  += v.x + v.y + v.z + v.w;
    s2 += v.x * v.x + v.y * v.y + v.z * v.z + v.w * v.w;
  }
#pragma unroll
  for (int o = 32; o > 0; o >>= 1) {
    s  += __shfl_down(s, o);
    s2 += __shfl_down(s2, o);
  }
  __shared__ float red[8];
  const int wid = t >> 6;
  if ((t & 63) == 0) { red[wid] = s; red[4 + wid] = s2; }
  __syncthreads();
  if (t == 0) {
    atomicAdd(&stats[b * 2 + 0], red[0] + red[1] + red[2] + red[3]);
    atomicAdd(&stats[b * 2 + 1], red[4] + red[5] + red[6] + red[7]);
  }
}

// ---------------- weight prep: fp32 -> bf16 ----------------
__global__ __launch_bounds__(256) void k_prep(const float* __restrict__ wq,
                                              const float* __restrict__ wk,
                                              const float* __restrict__ wv,
                                              const float* __restrict__ wo,
                                              unsigned short* __restrict__ wqb,
                                              unsigned short* __restrict__ wkvb,
                                              unsigned short* __restrict__ wob) {
  const int idx = blockIdx.x * 256 + threadIdx.x;
  if (idx < 65536) wqb[idx] = f2bf(wq[idx]);
  else if (idx < 81920) wkvb[idx - 65536] = f2bf(wk[idx - 65536]);
  else if (idx < 98304) wkvb[idx - 65536] = f2bf(wv[idx - 81920]);
  else if (idx < 163840) wob[idx - 98304] = f2bf(wo[idx - 98304]);
}

// ---------------- normalize + transpose: x[b][c][n] fp32 -> xnT[b][n][c] bf16 ----------------
__global__ __launch_bounds__(256) void k_xnt(const float* __restrict__ x,
                                             const float* __restrict__ gnw,
                                             const float* __restrict__ gnb,
                                             const float* __restrict__ stats,
                                             unsigned short* __restrict__ xnT) {
  __shared__ unsigned short T[64][72];   // [n_local][c_local], 144B row (16B-aligned)
  const int t = threadIdx.x;
  const int b = blockIdx.z, c0 = blockIdx.y * 64, n0 = blockIdx.x * 64;
  const float mu = stats[b * 2 + 0] * CNT_INV;
  const float rstd = rsqrtf(stats[b * 2 + 1] * CNT_INV - mu * mu + EPSV);
  const int nl = (t & 15) * 4, cl = t >> 4;
#pragma unroll
  for (int pass = 0; pass < 4; ++pass) {
    const int c = c0 + pass * 16 + cl;
    const float gw = gnw[c] * rstd;
    const float gb = gnb[c] - mu * rstd * gnw[c];
    float4 v = *(const float4*)&x[(size_t)(b * 256 + c) * 4096 + n0 + nl];
    T[nl + 0][pass * 16 + cl] = f2bf(v.x * gw + gb);
    T[nl + 1][pass * 16 + cl] = f2bf(v.y * gw + gb);
    T[nl + 2][pass * 16 + cl] = f2bf(v.z * gw + gb);
    T[nl + 3][pass * 16 + cl] = f2bf(v.w * gw + gb);
  }
  __syncthreads();
  const int r = t >> 2, cs = (t & 3) * 16;
  uint4 a = *(const uint4*)&T[r][cs];
  uint4 bb = *(const uint4*)&T[r][cs + 8];
  unsigned short* dst = xnT + ((size_t)b * 4096 + n0 + r) * 256 + c0 + cs;
  *(uint4*)dst = a;
  *(uint4*)(dst + 8) = bb;
}

// ---------------- pool: xnT rows -> xdsT[b][m][c] bf16 ----------------
__global__ __launch_bounds__(256) void k_poolT(const unsigned short* __restrict__ xnT,
                                               unsigned short* __restrict__ xdsT) {
  const int t = threadIdx.x;
  const int b = blockIdx.y;
  const int m = blockIdx.x * 8 + (t >> 5);
  const int cs = (t & 31) * 8;
  const int hd = m >> 5, wd = m & 31;
  const int r0 = hd * 128 + wd * 2;
  const unsigned short* base = xnT + (size_t)b * 4096 * 256 + cs;
  uint4 u0 = *(const uint4*)(base + (size_t)r0 * 256);
  uint4 u1 = *(const uint4*)(base + (size_t)(r0 + 1) * 256);
  uint4 u2 = *(const uint4*)(base + (size_t)(r0 + 64) * 256);
  uint4 u3 = *(const uint4*)(base + (size_t)(r0 + 65) * 256);
  const unsigned* p0 = (const unsigned*)&u0; const unsigned* p1 = (const unsigned*)&u1;
  const unsigned* p2 = (const unsigned*)&u2; const unsigned* p3 = (const unsigned*)&u3;
  unsigned out[4];
#pragma unroll
  for (int i = 0; i < 4; ++i) {
    float lo = (bf2f((unsigned short)p0[i]) + bf2f((unsigned short)p1[i]) +
                bf2f((unsigned short)p2[i]) + bf2f((unsigned short)p3[i])) * 0.25f;
    float hi = (bf2f((unsigned short)(p0[i] >> 16)) + bf2f((unsigned short)(p1[i] >> 16)) +
                bf2f((unsigned short)(p2[i] >> 16)) + bf2f((unsigned short)(p3[i] >> 16))) * 0.25f;
    out[i] = pk_rnd(lo, hi);
  }
  *(uint4*)(xdsT + ((size_t)b * 1024 + m) * 256 + cs) = *(uint4*)out;
}

// ---------------- Q gemm (MFMA, staging-free): qT[b][h][n][d] bf16 ----------------
__global__ __launch_bounds__(256) void k_gemm_q(const unsigned short* __restrict__ wqb,
                                                const unsigned short* __restrict__ xnT,
                                                unsigned short* __restrict__ qbf) {
  const int t = threadIdx.x;
  const int h = t >> 6, l = t & 63, lane16 = l & 15, quad = l >> 4;
  const int n0 = blockIdx.x * 64, b = blockIdx.y;
  f4_t acc[4][4];
#pragma unroll
  for (int i = 0; i < 4; ++i)
#pragma unroll
    for (int j = 0; j < 4; ++j) acc[i][j] = (f4_t){0.f, 0.f, 0.f, 0.f};
  for (int kc = 0; kc < 256; kc += 32) {
    bf8_t A[4], Bf[4];
#pragma unroll
    for (int og = 0; og < 4; ++og)
      A[og] = *(const bf8_t*)(wqb + (size_t)(h * 64 + og * 16 + lane16) * 256 + kc + quad * 8);
#pragma unroll
    for (int ng = 0; ng < 4; ++ng)
      Bf[ng] = *(const bf8_t*)(xnT + ((size_t)b * 4096 + n0 + ng * 16 + lane16) * 256 + kc + quad * 8);
#pragma unroll
    for (int og = 0; og < 4; ++og)
#pragma unroll
      for (int ng = 0; ng < 4; ++ng)
        acc[og][ng] = __builtin_amdgcn_mfma_f32_16x16x32_bf16(A[og], Bf[ng], acc[og][ng], 0, 0, 0);
  }
#pragma unroll
  for (int og = 0; og < 4; ++og)
#pragma unroll
    for (int ng = 0; ng < 4; ++ng) {
      const int n = n0 + ng * 16 + lane16;
      uint2 p;
      p.x = pk_rnd(acc[og][ng][0], acc[og][ng][1]);
      p.y = pk_rnd(acc[og][ng][2], acc[og][ng][3]);
      *(uint2*)(qbf + ((size_t)(b * 4 + h) * 4096 + n) * 64 + og * 16 + quad * 4) = p;
    }
}

// ---------------- K/V gemm (MFMA): k[b][m][d], vT[b][d][m] bf16 ----------------
__global__ __launch_bounds__(256) void k_gemm_kv(const unsigned short* __restrict__ wkvb,
                                                 const unsigned short* __restrict__ xdsT,
                                                 unsigned short* __restrict__ kbf,
                                                 unsigned short* __restrict__ vtbf) {
  const int t = threadIdx.x;
  const int w = t >> 6, l = t & 63, lane16 = l & 15, quad = l >> 4;
  const int m0 = blockIdx.x * 64, b = blockIdx.y;
  f4_t acc[2][4];
#pragma unroll
  for (int i = 0; i < 2; ++i)
#pragma unroll
    for (int j = 0; j < 4; ++j) acc[i][j] = (f4_t){0.f, 0.f, 0.f, 0.f};
  for (int kc = 0; kc < 256; kc += 32) {
    bf8_t A[2], Bf[4];
#pragma unroll
    for (int og = 0; og < 2; ++og)
      A[og] = *(const bf8_t*)(wkvb + (size_t)(w * 32 + og * 16 + lane16) * 256 + kc + quad * 8);
#pragma unroll
    for (int mg = 0; mg < 4; ++mg)
      Bf[mg] = *(const bf8_t*)(xdsT + ((size_t)b * 1024 + m0 + mg * 16 + lane16) * 256 + kc + quad * 8);
#pragma unroll
    for (int og = 0; og < 2; ++og)
#pragma unroll
      for (int mg = 0; mg < 4; ++mg)
        acc[og][mg] = __builtin_amdgcn_mfma_f32_16x16x32_bf16(A[og], Bf[mg], acc[og][mg], 0, 0, 0);
  }
  if (w < 2) {  // K: rows d = w*32+og*16+quad*4+r, col m -> kbf[m][d] 8B stores
#pragma unroll
    for (int og = 0; og < 2; ++og)
#pragma unroll
      for (int mg = 0; mg < 4; ++mg) {
        const int m = m0 + mg * 16 + lane16;
        uint2 p;
        p.x = pk_rnd(acc[og][mg][0], acc[og][mg][1]);
        p.y = pk_rnd(acc[og][mg][2], acc[og][mg][3]);
        *(uint2*)(kbf + (size_t)b * 65536 + (size_t)m * 64 + w * 32 + og * 16 + quad * 4) = p;
      }
  } else {  // V: vT[d][m] scalar stores
#pragma unroll
    for (int og = 0; og < 2; ++og)
#pragma unroll
      for (int mg = 0; mg < 4; ++mg) {
        const int m = m0 + mg * 16 + lane16;
        const int d0 = (w - 2) * 32 + og * 16 + quad * 4;
#pragma unroll
        for (int r = 0; r < 4; ++r)
          vtbf[(size_t)b * 65536 + (size_t)(d0 + r) * 1024 + m] = f2bf(acc[og][mg][r]);
      }
  }
}

// ---------------- MFMA attention: 64 q/wave, K/V prefetch, bf16 aoT out ----------------
__global__ __launch_bounds__(256) void k_attn_mfma(const unsigned short* __restrict__ qbf,
                                                   const unsigned short* __restrict__ kbf,
                                                   const unsigned short* __restrict__ vtbf,
                                                   unsigned short* __restrict__ aoT) {
  __shared__ __align__(16) unsigned short plds[4][64][36];  // per-wave P stage [q][kv]
  const int t = threadIdx.x;
  const int w = t >> 6, l = t & 63, lane16 = l & 15, quad = l >> 4;
  const int h = blockIdx.y, b = blockIdx.z;
  const int q0 = blockIdx.x * 256 + w * 64;

  const unsigned short* qb = qbf + ((size_t)(b * 4 + h) * 4096 + q0) * 64;
  const unsigned short* kb = kbf + (size_t)b * 65536;
  const unsigned short* vb = vtbf + (size_t)b * 65536;

  bf8_t Qf[4][2];
#pragma unroll
  for (int qg = 0; qg < 4; ++qg)
#pragma unroll
    for (int dc = 0; dc < 2; ++dc)
      Qf[qg][dc] = *(const bf8_t*)(qb + (qg * 16 + lane16) * 64 + dc * 32 + quad * 8);

  f4_t O[4][4];
#pragma unroll
  for (int dg = 0; dg < 4; ++dg)
#pragma unroll
    for (int qg = 0; qg < 4; ++qg) O[dg][qg] = (f4_t){0.f, 0.f, 0.f, 0.f};
  float den[4] = {0.f, 0.f, 0.f, 0.f};

  bf8_t Kc[2][2], Vc[4];
#pragma unroll
  for (int s = 0; s < 2; ++s)
#pragma unroll
    for (int dc = 0; dc < 2; ++dc)
      Kc[s][dc] = *(const bf8_t*)(kb + (size_t)(s * 16 + lane16) * 64 + dc * 32 + quad * 8);
#pragma unroll
  for (int dg = 0; dg < 4; ++dg)
    Vc[dg] = *(const bf8_t*)(vb + (size_t)(dg * 16 + lane16) * 1024 + quad * 8);

  for (int kv0 = 0; kv0 < 1024; kv0 += 32) {
    // prefetch next K/V tile (wraps harmlessly on last iter)
    const int kvn = (kv0 + 32) & 1023;
    bf8_t Kn[2][2], Vn[4];
#pragma unroll
    for (int s = 0; s < 2; ++s)
#pragma unroll
      for (int dc = 0; dc < 2; ++dc)
        Kn[s][dc] = *(const bf8_t*)(kb + (size_t)(kvn + s * 16 + lane16) * 64 + dc * 32 + quad * 8);
#pragma unroll
    for (int dg = 0; dg < 4; ++dg)
      Vn[dg] = *(const bf8_t*)(vb + (size_t)(dg * 16 + lane16) * 1024 + kvn + quad * 8);

    // S^T = K·Q^T, exp, pack to LDS
#pragma unroll
    for (int qg = 0; qg < 4; ++qg)
#pragma unroll
      for (int s = 0; s < 2; ++s) {
        f4_t S = (f4_t){0.f, 0.f, 0.f, 0.f};
        S = __builtin_amdgcn_mfma_f32_16x16x32_bf16(Kc[s][0], Qf[qg][0], S, 0, 0, 0);
        S = __builtin_amdgcn_mfma_f32_16x16x32_bf16(Kc[s][1], Qf[qg][1], S, 0, 0, 0);
        float e0 = __expf(S[0] * ATT_SCALE);
        float e1 = __expf(S[1] * ATT_SCALE);
        float e2 = __expf(S[2] * ATT_SCALE);
        float e3 = __expf(S[3] * ATT_SCALE);
        den[qg] += (e0 + e1) + (e2 + e3);
        uint2 p; p.x = pk_tr(e0, e1); p.y = pk_tr(e2, e3);
        *(uint2*)&plds[w][qg * 16 + lane16][s * 16 + quad * 4] = p;
      }

    bf8_t Pf[4];
#pragma unroll
    for (int qg = 0; qg < 4; ++qg)
      Pf[qg] = *(const bf8_t*)&plds[w][qg * 16 + lane16][quad * 8];
#pragma unroll
    for (int dg = 0; dg < 4; ++dg)
#pragma unroll
      for (int qg = 0; qg < 4; ++qg)
        O[dg][qg] = __builtin_amdgcn_mfma_f32_16x16x32_bf16(Vc[dg], Pf[qg], O[dg][qg], 0, 0, 0);

#pragma unroll
    for (int s = 0; s < 2; ++s)
#pragma unroll
      for (int dc = 0; dc < 2; ++dc) Kc[s][dc] = Kn[s][dc];
#pragma unroll
    for (int dg = 0; dg < 4; ++dg) Vc[dg] = Vn[dg];
  }

  float rden[4];
#pragma unroll
  for (int qg = 0; qg < 4; ++qg) {
    float d = den[qg];
    d += __shfl_xor(d, 16);
    d += __shfl_xor(d, 32);
    rden[qg] = 1.f / d;
  }

#pragma unroll
  for (int dg = 0; dg < 4; ++dg)
#pragma unroll
    for (int qg = 0; qg < 4; ++qg) {
      const int c0 = h * 64 + dg * 16 + quad * 4;
      const int n = q0 + qg * 16 + lane16;
      uint2 p;
      p.x = pk_rnd(O[dg][qg][0] * rden[qg], O[dg][qg][1] * rden[qg]);
      p.y = pk_rnd(O[dg][qg][2] * rden[qg], O[dg][qg][3] * rden[qg]);
      *(uint2*)(aoT + ((size_t)b * 4096 + n) * 256 + c0) = p;
    }
}

// ---------------- WO gemm (MFMA, staging-free) + residual ----------------
__global__ __launch_bounds__(256) void k_gemm_wo(const unsigned short* __restrict__ wob,
                                                 const unsigned short* __restrict__ aoT,
                                                 const float* __restrict__ x,
                                                 const float* __restrict__ gamma,
                                                 float* __restrict__ outp) {
  const int t = threadIdx.x;
  const int w = t >> 6, l = t & 63, lane16 = l & 15, quad = l >> 4;
  const int n0 = blockIdx.x * 64, b = blockIdx.y;
  f4_t acc[4][4];
#pragma unroll
  for (int i = 0; i < 4; ++i)
#pragma unroll
    for (int j = 0; j < 4; ++j) acc[i][j] = (f4_t){0.f, 0.f, 0.f, 0.f};
  for (int kc = 0; kc < 256; kc += 32) {
    bf8_t A[4], Bf[4];
#pragma unroll
    for (int og = 0; og < 4; ++og)
      A[og] = *(const bf8_t*)(wob + (size_t)(w * 64 + og * 16 + lane16) * 256 + kc + quad * 8);
#pragma unroll
    for (int ng = 0; ng < 4; ++ng)
      Bf[ng] = *(const bf8_t*)(aoT + ((size_t)b * 4096 + n0 + ng * 16 + lane16) * 256 + kc + quad * 8);
#pragma unroll
    for (int og = 0; og < 4; ++og)
#pragma unroll
      for (int ng = 0; ng < 4; ++ng)
        acc[og][ng] = __builtin_amdgcn_mfma_f32_16x16x32_bf16(A[og], Bf[ng], acc[og][ng], 0, 0, 0);
  }
#pragma unroll
  for (int og = 0; og < 4; ++og) {
    float4 g4 = *(const float4*)&gamma[w * 64 + og * 16 + quad * 4];
    const float g[4] = {g4.x, g4.y, g4.z, g4.w};
#pragma unroll
    for (int ng = 0; ng < 4; ++ng) {
      const int n = n0 + ng * 16 + lane16;
#pragma unroll
      for (int r = 0; r < 4; ++r) {
        const int o = w * 64 + og * 16 + quad * 4 + r;
        const size_t ix = ((size_t)(b * 256 + o)) * 4096 + n;
        outp[ix] = x[ix] + g[r] * acc[og][ng][r];
      }
    }
  }
}

extern "C" void kernel_launch(void* const* d_in, const int* in_sizes, int n_in,
                              void* d_out, int out_size, void* d_ws, size_t ws_size,
                              hipStream_t stream) {
  const float* x     = (const float*)d_in[0];
  const float* gnw   = (const float*)d_in[1];
  const float* gnb   = (const float*)d_in[2];
  const float* wq    = (const float*)d_in[3];
  const float* wk    = (const float*)d_in[4];
  const float* wv    = (const float*)d_in[5];
  const float* wo    = (const float*)d_in[6];
  const float* gamma = (const float*)d_in[7];
  float* out = (float*)d_out;
  float* ws  = (float*)d_ws;
  unsigned short* xnT  = (unsigned short*)(ws + WS_XNT);
  unsigned short* xdsT = (unsigned short*)(ws + WS_XDS);
  unsigned short* qbf  = (unsigned short*)(ws + WS_Q);
  unsigned short* kbf  = (unsigned short*)(ws + WS_K);
  unsigned short* vtbf = (unsigned short*)(ws + WS_V);
  unsigned short* aoT  = (unsigned short*)(ws + WS_AOT);
  unsigned short* wqb  = (unsigned short*)(ws + WS_WQB);
  unsigned short* wkvb = (unsigned short*)(ws + WS_WKV);
  unsigned short* wob  = (unsigned short*)(ws + WS_WOB);

  hipMemsetAsync(ws, 0, 256, stream);
  k_prep<<<640, 256, 0, stream>>>(wq, wk, wv, wo, wqb, wkvb, wob);
  k_stats<<<512, 256, 0, stream>>>(x, ws + WS_STATS);
  k_xnt<<<dim3(64, 4, 8), 256, 0, stream>>>(x, gnw, gnb, ws + WS_STATS, xnT);
  k_poolT<<<dim3(128, 8), 256, 0, stream>>>(xnT, xdsT);
  k_gemm_q<<<dim3(64, 8), 256, 0, stream>>>(wqb, xnT, qbf);
  k_gemm_kv<<<dim3(16, 8), 256, 0, stream>>>(wkvb, xdsT, kbf, vtbf);
  k_attn_mfma<<<dim3(16, 4, 8), 256, 0, stream>>>(qbf, kbf, vtbf, aoT);
  k_gemm_wo<<<dim3(64, 8), 256, 0, stream>>>(wob, aoT, x, gamma, out);
}

// Round 4
// 253.008 us; speedup vs baseline: 4.6217x; 1.0206x over previous
//
#include <hip/hip_runtime.h>

// MobileMQA: B=8, C=256, H=W=64, NUM_HEADS=4, hd=64, ds=2
// R4: attention with 2-way KV split per block (2x TLP, linear partial combine),
//     scale*log2e folded into Q + raw v_exp_f32, prep+stats merged, pool fused into xnt.

#define CNT_INV (1.0f/1048576.0f)
#define EPSV 1e-5f
#define QSCALE 0.18033688f   // 0.125 * log2(e), folded into Q so exp becomes v_exp_f32(S)

// workspace layout (float offsets)
#define WS_STATS 0                    // 64
#define WS_XNT   64                   // bf16 xnT [b][n][c]  = 4,194,304 f
#define WS_XDS   4194368              // bf16 xdsT [b][m][c] = 1,048,576 f
#define WS_Q     5242944              // bf16 qT  [b][h][n][d] = 4,194,304 f
#define WS_K     9437248              // bf16 k   [b][m][d]  = 262,144 f
#define WS_V     9699392              // bf16 vT  [b][d][m]  = 262,144 f
#define WS_AOT   9961536              // bf16 aoT [b][n][c]  = 4,194,304 f
#define WS_WQB   14155840             // bf16 wq  [o][c]     = 32,768 f
#define WS_WKV   14188608             // bf16 [wk;wv]        = 16,384 f
#define WS_WOB   14204992             // bf16 wo  [o][c]     = 32,768 f

typedef __attribute__((ext_vector_type(8))) short bf8_t;   // 8 bf16 MFMA A/B frag
typedef __attribute__((ext_vector_type(4))) float f4_t;    // MFMA C/D frag

static __device__ __forceinline__ unsigned fbits(float f) {
  union { float f; unsigned u; } v; v.f = f; return v.u;
}
static __device__ __forceinline__ unsigned short f2bf(float f) {  // RNE
  unsigned u = fbits(f);
  return (unsigned short)((u + 0x7fffu + ((u >> 16) & 1u)) >> 16);
}
static __device__ __forceinline__ unsigned pk_rnd(float a, float b) {
  return __builtin_amdgcn_perm(fbits(b) + 0x8000u, fbits(a) + 0x8000u, 0x07060302u);
}
static __device__ __forceinline__ unsigned pk_tr(float a, float b) {
  return __builtin_amdgcn_perm(fbits(b), fbits(a), 0x07060302u);
}
static __device__ __forceinline__ float bf2f(unsigned short h) {
  union { unsigned u; float f; } v; v.u = ((unsigned)h) << 16; return v.f;
}
static __device__ __forceinline__ float fexp2(float x) {   // 2^x, raw v_exp_f32
  float r; asm("v_exp_f32 %0, %1" : "=v"(r) : "v"(x)); return r;
}

// ---------------- merged: weight prep (blocks >= 512) + stats (blocks < 512) ----------------
__global__ __launch_bounds__(256) void k_prep_stats(const float* __restrict__ x,
                                                    const float* __restrict__ wq,
                                                    const float* __restrict__ wk,
                                                    const float* __restrict__ wv,
                                                    const float* __restrict__ wo,
                                                    float* __restrict__ stats,
                                                    unsigned short* __restrict__ wqb,
                                                    unsigned short* __restrict__ wkvb,
                                                    unsigned short* __restrict__ wob) {
  const int blk = blockIdx.x;
  const int t = threadIdx.x;
  if (blk < 512) {
    const int b = blk >> 6;
    const int chunk = blk & 63;
    const float4* xb = (const float4*)(x + (size_t)b * 1048576 + (size_t)chunk * 16384);
    float s = 0.f, s2 = 0.f;
#pragma unroll
    for (int it = 0; it < 16; ++it) {
      float4 v = xb[it * 256 + t];
      s  += v.x + v.y + v.z + v.w;
      s2 += v.x * v.x + v.y * v.y + v.z * v.z + v.w * v.w;
    }
#pragma unroll
    for (int o = 32; o > 0; o >>= 1) {
      s  += __shfl_down(s, o);
      s2 += __shfl_down(s2, o);
    }
    __shared__ float red[8];
    const int wid = t >> 6;
    if ((t & 63) == 0) { red[wid] = s; red[4 + wid] = s2; }
    __syncthreads();
    if (t == 0) {
      atomicAdd(&stats[b * 2 + 0], red[0] + red[1] + red[2] + red[3]);
      atomicAdd(&stats[b * 2 + 1], red[4] + red[5] + red[6] + red[7]);
    }
  } else {
    const int idx = (blk - 512) * 256 + t;
    if (idx < 65536) wqb[idx] = f2bf(wq[idx]);
    else if (idx < 81920) wkvb[idx - 65536] = f2bf(wk[idx - 65536]);
    else if (idx < 98304) wkvb[idx - 65536] = f2bf(wv[idx - 81920]);
    else if (idx < 163840) wob[idx - 98304] = f2bf(wo[idx - 98304]);
  }
}

// ---------------- normalize + transpose + fused 2x2 pool ----------------
// block: h-pair (128 n) x 64 c; writes xnT[b][n][c] and xdsT[b][m][c]
__global__ __launch_bounds__(256) void k_xnt(const float* __restrict__ x,
                                             const float* __restrict__ gnw,
                                             const float* __restrict__ gnb,
                                             const float* __restrict__ stats,
                                             unsigned short* __restrict__ xnT,
                                             unsigned short* __restrict__ xdsT) {
  __shared__ unsigned short T[128][72];   // [n_local][c_local]
  const int t = threadIdx.x;
  const int b = blockIdx.z, c0 = blockIdx.y * 64, hp = blockIdx.x;
  const int n0 = hp * 128;
  const float mu = stats[b * 2 + 0] * CNT_INV;
  const float rstd = rsqrtf(stats[b * 2 + 1] * CNT_INV - mu * mu + EPSV);
  const int n4 = (t & 31) * 4, cl = t >> 5;
#pragma unroll
  for (int p = 0; p < 8; ++p) {
    const int c = c0 + p * 8 + cl;
    const float gw = gnw[c] * rstd;
    const float gb = gnb[c] - mu * rstd * gnw[c];
    float4 v = *(const float4*)&x[(size_t)(b * 256 + c) * 4096 + n0 + n4];
    T[n4 + 0][p * 8 + cl] = f2bf(v.x * gw + gb);
    T[n4 + 1][p * 8 + cl] = f2bf(v.y * gw + gb);
    T[n4 + 2][p * 8 + cl] = f2bf(v.z * gw + gb);
    T[n4 + 3][p * 8 + cl] = f2bf(v.w * gw + gb);
  }
  __syncthreads();
  {  // write xnT: 128 rows x 64 c
    const int r = t >> 1, ch = (t & 1) * 32;
    unsigned short* dst = xnT + ((size_t)b * 4096 + n0 + r) * 256 + c0 + ch;
#pragma unroll
    for (int u = 0; u < 4; ++u)
      *(uint4*)(dst + u * 8) = *(const uint4*)&T[r][ch + u * 8];
  }
  {  // fused pool: 32 m x 64 c
    const int wd = t & 31, c8 = (t >> 5) * 8;
    uint4 u0 = *(const uint4*)&T[2 * wd][c8];
    uint4 u1 = *(const uint4*)&T[2 * wd + 1][c8];
    uint4 u2 = *(const uint4*)&T[64 + 2 * wd][c8];
    uint4 u3 = *(const uint4*)&T[64 + 2 * wd + 1][c8];
    const unsigned* p0 = (const unsigned*)&u0; const unsigned* p1 = (const unsigned*)&u1;
    const unsigned* p2 = (const unsigned*)&u2; const unsigned* p3 = (const unsigned*)&u3;
    unsigned outp[4];
#pragma unroll
    for (int i = 0; i < 4; ++i) {
      float lo = (bf2f((unsigned short)p0[i]) + bf2f((unsigned short)p1[i]) +
                  bf2f((unsigned short)p2[i]) + bf2f((unsigned short)p3[i])) * 0.25f;
      float hi = (bf2f((unsigned short)(p0[i] >> 16)) + bf2f((unsigned short)(p1[i] >> 16)) +
                  bf2f((unsigned short)(p2[i] >> 16)) + bf2f((unsigned short)(p3[i] >> 16))) * 0.25f;
      outp[i] = pk_rnd(lo, hi);
    }
    *(uint4*)(xdsT + ((size_t)b * 1024 + hp * 32 + wd) * 256 + c0 + c8) = *(uint4*)outp;
  }
}

// ---------------- Q gemm (MFMA, staging-free): qT bf16, scaled by 0.125*log2e ----------------
__global__ __launch_bounds__(256) void k_gemm_q(const unsigned short* __restrict__ wqb,
                                                const unsigned short* __restrict__ xnT,
                                                unsigned short* __restrict__ qbf) {
  const int t = threadIdx.x;
  const int h = t >> 6, l = t & 63, lane16 = l & 15, quad = l >> 4;
  const int n0 = blockIdx.x * 64, b = blockIdx.y;
  f4_t acc[4][4];
#pragma unroll
  for (int i = 0; i < 4; ++i)
#pragma unroll
    for (int j = 0; j < 4; ++j) acc[i][j] = (f4_t){0.f, 0.f, 0.f, 0.f};
  for (int kc = 0; kc < 256; kc += 32) {
    bf8_t A[4], Bf[4];
#pragma unroll
    for (int og = 0; og < 4; ++og)
      A[og] = *(const bf8_t*)(wqb + (size_t)(h * 64 + og * 16 + lane16) * 256 + kc + quad * 8);
#pragma unroll
    for (int ng = 0; ng < 4; ++ng)
      Bf[ng] = *(const bf8_t*)(xnT + ((size_t)b * 4096 + n0 + ng * 16 + lane16) * 256 + kc + quad * 8);
#pragma unroll
    for (int og = 0; og < 4; ++og)
#pragma unroll
      for (int ng = 0; ng < 4; ++ng)
        acc[og][ng] = __builtin_amdgcn_mfma_f32_16x16x32_bf16(A[og], Bf[ng], acc[og][ng], 0, 0, 0);
  }
#pragma unroll
  for (int og = 0; og < 4; ++og)
#pragma unroll
    for (int ng = 0; ng < 4; ++ng) {
      const int n = n0 + ng * 16 + lane16;
      uint2 p;
      p.x = pk_rnd(acc[og][ng][0] * QSCALE, acc[og][ng][1] * QSCALE);
      p.y = pk_rnd(acc[og][ng][2] * QSCALE, acc[og][ng][3] * QSCALE);
      *(uint2*)(qbf + ((size_t)(b * 4 + h) * 4096 + n) * 64 + og * 16 + quad * 4) = p;
    }
}

// ---------------- K/V gemm (MFMA): k[b][m][d], vT[b][d][m] bf16 ----------------
__global__ __launch_bounds__(256) void k_gemm_kv(const unsigned short* __restrict__ wkvb,
                                                 const unsigned short* __restrict__ xdsT,
                                                 unsigned short* __restrict__ kbf,
                                                 unsigned short* __restrict__ vtbf) {
  const int t = threadIdx.x;
  const int w = t >> 6, l = t & 63, lane16 = l & 15, quad = l >> 4;
  const int m0 = blockIdx.x * 64, b = blockIdx.y;
  f4_t acc[2][4];
#pragma unroll
  for (int i = 0; i < 2; ++i)
#pragma unroll
    for (int j = 0; j < 4; ++j) acc[i][j] = (f4_t){0.f, 0.f, 0.f, 0.f};
  for (int kc = 0; kc < 256; kc += 32) {
    bf8_t A[2], Bf[4];
#pragma unroll
    for (int og = 0; og < 2; ++og)
      A[og] = *(const bf8_t*)(wkvb + (size_t)(w * 32 + og * 16 + lane16) * 256 + kc + quad * 8);
#pragma unroll
    for (int mg = 0; mg < 4; ++mg)
      Bf[mg] = *(const bf8_t*)(xdsT + ((size_t)b * 1024 + m0 + mg * 16 + lane16) * 256 + kc + quad * 8);
#pragma unroll
    for (int og = 0; og < 2; ++og)
#pragma unroll
      for (int mg = 0; mg < 4; ++mg)
        acc[og][mg] = __builtin_amdgcn_mfma_f32_16x16x32_bf16(A[og], Bf[mg], acc[og][mg], 0, 0, 0);
  }
  if (w < 2) {  // K -> kbf[m][d]
#pragma unroll
    for (int og = 0; og < 2; ++og)
#pragma unroll
      for (int mg = 0; mg < 4; ++mg) {
        const int m = m0 + mg * 16 + lane16;
        uint2 p;
        p.x = pk_rnd(acc[og][mg][0], acc[og][mg][1]);
        p.y = pk_rnd(acc[og][mg][2], acc[og][mg][3]);
        *(uint2*)(kbf + (size_t)b * 65536 + (size_t)m * 64 + w * 32 + og * 16 + quad * 4) = p;
      }
  } else {  // V -> vT[d][m]
#pragma unroll
    for (int og = 0; og < 2; ++og)
#pragma unroll
      for (int mg = 0; mg < 4; ++mg) {
        const int m = m0 + mg * 16 + lane16;
        const int d0 = (w - 2) * 32 + og * 16 + quad * 4;
#pragma unroll
        for (int r = 0; r < 4; ++r)
          vtbf[(size_t)b * 65536 + (size_t)(d0 + r) * 1024 + m] = f2bf(acc[og][mg][r]);
      }
  }
}

// ---------------- MFMA attention: 2 waves/block, KV split, linear partial combine ----------------
__global__ __launch_bounds__(128) void k_attn_mfma(const unsigned short* __restrict__ qbf,
                                                   const unsigned short* __restrict__ kbf,
                                                   const unsigned short* __restrict__ vtbf,
                                                   unsigned short* __restrict__ aoT) {
  __shared__ __align__(16) char smem[17408];
  unsigned short (*plds)[64][36] = (unsigned short (*)[64][36])smem;  // [2][64][36] u16
  f4_t (*rbuf)[64] = (f4_t (*)[64])smem;                              // [17][64] f4 (after loop)
  const int t = threadIdx.x;
  const int w = t >> 6, l = t & 63, lane16 = l & 15, quad = l >> 4;
  const int h = blockIdx.y, b = blockIdx.z;
  const int q0 = blockIdx.x * 64;

  const unsigned short* qb = qbf + ((size_t)(b * 4 + h) * 4096 + q0) * 64;
  const unsigned short* kb = kbf + (size_t)b * 65536;
  const unsigned short* vb = vtbf + (size_t)b * 65536;

  bf8_t Qf[4][2];
#pragma unroll
  for (int qg = 0; qg < 4; ++qg)
#pragma unroll
    for (int dc = 0; dc < 2; ++dc)
      Qf[qg][dc] = *(const bf8_t*)(qb + (qg * 16 + lane16) * 64 + dc * 32 + quad * 8);

  f4_t O[4][4];
#pragma unroll
  for (int dg = 0; dg < 4; ++dg)
#pragma unroll
    for (int qg = 0; qg < 4; ++qg) O[dg][qg] = (f4_t){0.f, 0.f, 0.f, 0.f};
  float den[4] = {0.f, 0.f, 0.f, 0.f};

  const int kvbase = w * 512;
  bf8_t Kc[2][2], Vc[4];
#pragma unroll
  for (int s = 0; s < 2; ++s)
#pragma unroll
    for (int dc = 0; dc < 2; ++dc)
      Kc[s][dc] = *(const bf8_t*)(kb + (size_t)(kvbase + s * 16 + lane16) * 64 + dc * 32 + quad * 8);
#pragma unroll
  for (int dg = 0; dg < 4; ++dg)
    Vc[dg] = *(const bf8_t*)(vb + (size_t)(dg * 16 + lane16) * 1024 + kvbase + quad * 8);

  for (int it = 0; it < 16; ++it) {
    const int kvn = kvbase + (((it + 1) & 15) * 32);
    bf8_t Kn[2][2], Vn[4];
#pragma unroll
    for (int s = 0; s < 2; ++s)
#pragma unroll
      for (int dc = 0; dc < 2; ++dc)
        Kn[s][dc] = *(const bf8_t*)(kb + (size_t)(kvn + s * 16 + lane16) * 64 + dc * 32 + quad * 8);
#pragma unroll
    for (int dg = 0; dg < 4; ++dg)
      Vn[dg] = *(const bf8_t*)(vb + (size_t)(dg * 16 + lane16) * 1024 + kvn + quad * 8);

#pragma unroll
    for (int qg = 0; qg < 4; ++qg)
#pragma unroll
      for (int s = 0; s < 2; ++s) {
        f4_t S = (f4_t){0.f, 0.f, 0.f, 0.f};
        S = __builtin_amdgcn_mfma_f32_16x16x32_bf16(Kc[s][0], Qf[qg][0], S, 0, 0, 0);
        S = __builtin_amdgcn_mfma_f32_16x16x32_bf16(Kc[s][1], Qf[qg][1], S, 0, 0, 0);
        float e0 = fexp2(S[0]);
        float e1 = fexp2(S[1]);
        float e2 = fexp2(S[2]);
        float e3 = fexp2(S[3]);
        den[qg] += (e0 + e1) + (e2 + e3);
        uint2 p; p.x = pk_tr(e0, e1); p.y = pk_tr(e2, e3);
        *(uint2*)&plds[w][qg * 16 + lane16][s * 16 + quad * 4] = p;
      }

    bf8_t Pf[4];
#pragma unroll
    for (int qg = 0; qg < 4; ++qg)
      Pf[qg] = *(const bf8_t*)&plds[w][qg * 16 + lane16][quad * 8];
#pragma unroll
    for (int dg = 0; dg < 4; ++dg)
#pragma unroll
      for (int qg = 0; qg < 4; ++qg)
        O[dg][qg] = __builtin_amdgcn_mfma_f32_16x16x32_bf16(Vc[dg], Pf[qg], O[dg][qg], 0, 0, 0);

#pragma unroll
    for (int s = 0; s < 2; ++s)
#pragma unroll
      for (int dc = 0; dc < 2; ++dc) Kc[s][dc] = Kn[s][dc];
#pragma unroll
    for (int dg = 0; dg < 4; ++dg) Vc[dg] = Vn[dg];
  }

  // reduce den across quads within wave (lanes with same lane16 hold same value after)
#pragma unroll
  for (int qg = 0; qg < 4; ++qg) {
    den[qg] += __shfl_xor(den[qg], 16);
    den[qg] += __shfl_xor(den[qg], 32);
  }

  __syncthreads();   // both waves done with plds; smem reused as rbuf
  if (w == 1) {
#pragma unroll
    for (int dg = 0; dg < 4; ++dg)
#pragma unroll
      for (int qg = 0; qg < 4; ++qg) rbuf[dg * 4 + qg][l] = O[dg][qg];
    rbuf[16][l] = (f4_t){den[0], den[1], den[2], den[3]};
  }
  __syncthreads();
  if (w == 0) {
    f4_t dp = rbuf[16][l];
    float rden[4];
#pragma unroll
    for (int qg = 0; qg < 4; ++qg) rden[qg] = 1.f / (den[qg] + dp[qg]);
#pragma unroll
    for (int dg = 0; dg < 4; ++dg)
#pragma unroll
      for (int qg = 0; qg < 4; ++qg) {
        f4_t o2 = rbuf[dg * 4 + qg][l];
        const int c0 = h * 64 + dg * 16 + quad * 4;
        const int n = q0 + qg * 16 + lane16;
        uint2 p;
        p.x = pk_rnd((O[dg][qg][0] + o2[0]) * rden[qg], (O[dg][qg][1] + o2[1]) * rden[qg]);
        p.y = pk_rnd((O[dg][qg][2] + o2[2]) * rden[qg], (O[dg][qg][3] + o2[3]) * rden[qg]);
        *(uint2*)(aoT + ((size_t)b * 4096 + n) * 256 + c0) = p;
      }
  }
}

// ---------------- WO gemm (MFMA, staging-free) + residual ----------------
__global__ __launch_bounds__(256) void k_gemm_wo(const unsigned short* __restrict__ wob,
                                                 const unsigned short* __restrict__ aoT,
                                                 const float* __restrict__ x,
                                                 const float* __restrict__ gamma,
                                                 float* __restrict__ outp) {
  const int t = threadIdx.x;
  const int w = t >> 6, l = t & 63, lane16 = l & 15, quad = l >> 4;
  const int n0 = blockIdx.x * 64, b = blockIdx.y;
  f4_t acc[4][4];
#pragma unroll
  for (int i = 0; i < 4; ++i)
#pragma unroll
    for (int j = 0; j < 4; ++j) acc[i][j] = (f4_t){0.f, 0.f, 0.f, 0.f};
  for (int kc = 0; kc < 256; kc += 32) {
    bf8_t A[4], Bf[4];
#pragma unroll
    for (int og = 0; og < 4; ++og)
      A[og] = *(const bf8_t*)(wob + (size_t)(w * 64 + og * 16 + lane16) * 256 + kc + quad * 8);
#pragma unroll
    for (int ng = 0; ng < 4; ++ng)
      Bf[ng] = *(const bf8_t*)(aoT + ((size_t)b * 4096 + n0 + ng * 16 + lane16) * 256 + kc + quad * 8);
#pragma unroll
    for (int og = 0; og < 4; ++og)
#pragma unroll
      for (int ng = 0; ng < 4; ++ng)
        acc[og][ng] = __builtin_amdgcn_mfma_f32_16x16x32_bf16(A[og], Bf[ng], acc[og][ng], 0, 0, 0);
  }
#pragma unroll
  for (int og = 0; og < 4; ++og) {
    float4 g4 = *(const float4*)&gamma[w * 64 + og * 16 + quad * 4];
    const float g[4] = {g4.x, g4.y, g4.z, g4.w};
#pragma unroll
    for (int ng = 0; ng < 4; ++ng) {
      const int n = n0 + ng * 16 + lane16;
#pragma unroll
      for (int r = 0; r < 4; ++r) {
        const int o = w * 64 + og * 16 + quad * 4 + r;
        const size_t ix = ((size_t)(b * 256 + o)) * 4096 + n;
        outp[ix] = x[ix] + g[r] * acc[og][ng][r];
      }
    }
  }
}

extern "C" void kernel_launch(void* const* d_in, const int* in_sizes, int n_in,
                              void* d_out, int out_size, void* d_ws, size_t ws_size,
                              hipStream_t stream) {
  const float* x     = (const float*)d_in[0];
  const float* gnw   = (const float*)d_in[1];
  const float* gnb   = (const float*)d_in[2];
  const float* wq    = (const float*)d_in[3];
  const float* wk    = (const float*)d_in[4];
  const float* wv    = (const float*)d_in[5];
  const float* wo    = (const float*)d_in[6];
  const float* gamma = (const float*)d_in[7];
  float* out = (float*)d_out;
  float* ws  = (float*)d_ws;
  unsigned short* xnT  = (unsigned short*)(ws + WS_XNT);
  unsigned short* xdsT = (unsigned short*)(ws + WS_XDS);
  unsigned short* qbf  = (unsigned short*)(ws + WS_Q);
  unsigned short* kbf  = (unsigned short*)(ws + WS_K);
  unsigned short* vtbf = (unsigned short*)(ws + WS_V);
  unsigned short* aoT  = (unsigned short*)(ws + WS_AOT);
  unsigned short* wqb  = (unsigned short*)(ws + WS_WQB);
  unsigned short* wkvb = (unsigned short*)(ws + WS_WKV);
  unsigned short* wob  = (unsigned short*)(ws + WS_WOB);

  hipMemsetAsync(ws, 0, 256, stream);
  k_prep_stats<<<1152, 256, 0, stream>>>(x, wq, wk, wv, wo, ws + WS_STATS, wqb, wkvb, wob);
  k_xnt<<<dim3(32, 4, 8), 256, 0, stream>>>(x, gnw, gnb, ws + WS_STATS, xnT, xdsT);
  k_gemm_q<<<dim3(64, 8), 256, 0, stream>>>(wqb, xnT, qbf);
  k_gemm_kv<<<dim3(16, 8), 256, 0, stream>>>(wkvb, xdsT, kbf, vtbf);
  k_attn_mfma<<<dim3(64, 4, 8), 128, 0, stream>>>(qbf, kbf, vtbf, aoT);
  k_gemm_wo<<<dim3(64, 8), 256, 0, stream>>>(wob, aoT, x, gamma, out);
}